// Round 9
// baseline (214.334 us; speedup 1.0000x reference)
//
#include <hip/hip_runtime.h>

typedef _Float16 f16;
typedef _Float16 f16x8 __attribute__((ext_vector_type(8)));
typedef float    f32x4 __attribute__((ext_vector_type(4)));

#define HO 62
#define WO 62

// ---------- shared device helpers ----------

__device__ __forceinline__ void build_bfrag(int nn, int kb,
    const float* __restrict__ bw, const float* __restrict__ sw,
    const float* __restrict__ sc, f16x8 bfrag[3][2])
{
    #pragma unroll
    for (int ki = 0; ki < 3; ++ki) {
        #pragma unroll
        for (int kjp = 0; kjp < 2; ++kjp) {
            f16x8 bf;
            #pragma unroll
            for (int e = 0; e < 8; ++e) {
                const int k    = kb * 8 + e;
                const int kj   = kjp * 2 + (k >> 4);
                const int slot = k & 15;
                float wv = 0.0f;
                if (nn < 8 && kj < 3 && slot < 9) {
                    const int kk = ki * 3 + kj;
                    wv = (slot == 0) ? bw[nn * 9 + kk]
                                     : sw[(nn * 9 + kk) * 8 + (slot - 1)] * sc[nn * 9 + kk];
                }
                bf[e] = (f16)wv;
            }
            bfrag[ki][kjp] = bf;
        }
    }
}

__device__ __forceinline__ void stage1(f16* __restrict__ wfeat,
    const float* __restrict__ xp, int r0, int c0, int lane,
    float g0, float inv_h)
{
    #pragma unroll
    for (int it = 0; it < 3; ++it) {
        const int p = it * 64 + lane;
        if (p < 180) {
            const int row = p / 18;
            const int col = p - row * 18;
            int gy = r0 + row; gy = (gy < 64) ? gy : 63;
            int gx = c0 + col; gx = (gx < 64) ? gx : 63;
            const float xv = xp[gy * 64 + gx];

            const float s = xv / (1.0f + __expf(-xv));
            const float u = (xv - g0) * inv_h;
            int j = (int)floorf(u);
            j = (j < 3) ? 3 : ((j > 7) ? 7 : j);
            const float t   = u - (float)j;
            const float omt = 1.0f - t;
            const float t2  = t * t;
            const float t3  = t2 * t;
            const float c6  = 1.0f / 6.0f;
            const float bv0 = omt * omt * omt * c6;
            const float bv1 = (3.0f * t3 - 6.0f * t2 + 4.0f) * c6;
            const float bv2 = (-3.0f * t3 + 3.0f * t2 + 3.0f * t + 1.0f) * c6;
            const float bv3 = t3 * c6;

            f16* fp = &wfeat[p * 16];
            f16x8 z0 = {(f16)s, (f16)0.f, (f16)0.f, (f16)0.f,
                        (f16)0.f, (f16)0.f, (f16)0.f, (f16)0.f};
            f16x8 z1 = {(f16)0.f, (f16)0.f, (f16)0.f, (f16)0.f,
                        (f16)0.f, (f16)0.f, (f16)0.f, (f16)0.f};
            *(f16x8*)fp       = z0;
            *(f16x8*)(fp + 8) = z1;
            fp[j - 2] = (f16)bv0;
            fp[j - 1] = (f16)bv1;
            fp[j]     = (f16)bv2;
            fp[j + 1] = (f16)bv3;
        }
    }
}

// ---------- F: real kernel (R8 + bfrag amortized over 4 tiles/wave) ----------
// 512 blocks x 256 thr (4 waves). Wave gid = bx*4+w owns (plane=gid>>3,
// chunk=gid&7) and loops its 4 col-tiles. No __syncthreads (wave-private LDS).
__global__ __launch_bounds__(256, 2) void kan_f(
    const float* __restrict__ x, const float* __restrict__ grid_,
    const float* __restrict__ bw, const float* __restrict__ sw,
    const float* __restrict__ sc, float* __restrict__ out)
{
    __shared__ __align__(16) f16 feat[12032];   // 4x2880 + pad for kj=3 dead reads

    const int tid  = threadIdx.x;
    const int lane = tid & 63;
    const int w    = tid >> 6;
    f16* wfeat = &feat[w * 2880];

    const int gid   = blockIdx.x * 4 + w;
    const int nn    = lane & 15;
    const int kb    = lane >> 4;
    const int mI    = lane & 15;
    const int khalf = kb & 1;
    const int cAdd  = kb >> 1;

    f16x8 bfrag[3][2];
    build_bfrag(nn, kb, bw, sw, sc, bfrag);     // ONCE per wave (was per tile)

    const float g0    = grid_[0];
    const float inv_h = 1.0f / (grid_[1] - grid_[0]);
    const int plane = gid >> 3;
    const int chunk = gid & 7;
    const int r0    = chunk * 8;
    const float* xp = x + (size_t)plane * 4096;

    for (int s = 0; s < 4; ++s) {
        const int c0 = s * 16;
        stage1(wfeat, xp, r0, c0, lane, g0, inv_h);

        const int aBase = (mI + cAdd) * 16 + khalf * 8;
        f16x8 af[3][2];
        #pragma unroll
        for (int kjp = 0; kjp < 2; ++kjp) {
            af[0][kjp] = *(const f16x8*)&wfeat[aBase + kjp * 32 + 0 * 288];
            af[1][kjp] = *(const f16x8*)&wfeat[aBase + kjp * 32 + 1 * 288];
        }
        #pragma unroll
        for (int i = 0; i < 8; ++i) {
            #pragma unroll
            for (int kjp = 0; kjp < 2; ++kjp)
                af[(i + 2) % 3][kjp] =
                    *(const f16x8*)&wfeat[aBase + kjp * 32 + (i + 2) * 288];
            f32x4 acc = {0.f, 0.f, 0.f, 0.f};
            #pragma unroll
            for (int ki = 0; ki < 3; ++ki)
                #pragma unroll
                for (int kjp = 0; kjp < 2; ++kjp)
                    acc = __builtin_amdgcn_mfma_f32_16x16x32_f16(
                              af[(i + ki) % 3][kjp], bfrag[ki][kjp], acc, 0, 0, 0);
            const int ho = r0 + i;
            if (nn < 8 && ho < HO) {
                const int cb = c0 + kb * 4;
                float* po = out + ((size_t)(plane * 8 + nn) * (HO * WO)) + ho * WO + cb;
                if (cb + 3 < WO) {
                    float2 lo = {acc[0], acc[1]};
                    float2 hi = {acc[2], acc[3]};
                    *(float2*)po       = lo;
                    *(float2*)(po + 2) = hi;
                } else {
                    #pragma unroll
                    for (int q = 0; q < 4; ++q)
                        if (cb + q < WO) po[q] = acc[q];
                }
            }
        }
    }
}

// ---------- E: store-pattern ablation (targets d_ws, not out) x6 ----------
__global__ __launch_bounds__(256, 2) void kan_e_store(float* __restrict__ wsf)
{
    const int tid  = threadIdx.x;
    const int lane = tid & 63;
    const int w    = tid >> 6;
    const int gid  = blockIdx.x * 4 + w;
    const int nn   = lane & 15;
    const int kb   = lane >> 4;
    const int plane = gid >> 3;
    const int chunk = gid & 7;
    const int r0    = chunk * 8;

    for (int rep = 0; rep < 6; ++rep) {
        for (int s = 0; s < 4; ++s) {
            const int c0 = s * 16;
            #pragma unroll
            for (int i = 0; i < 8; ++i) {
                const int ho = r0 + i;
                if (nn < 8 && ho < HO) {
                    const int cb = c0 + kb * 4;
                    float* po = wsf + ((size_t)(plane * 8 + nn) * (HO * WO)) + ho * WO + cb;
                    float z0 = 0.f, z1 = 0.f, z2 = 0.f, z3 = 0.f;
                    asm volatile("" : "+v"(z0), "+v"(z1), "+v"(z2), "+v"(z3));
                    if (cb + 3 < WO) {
                        float2 lo = {z0, z1};
                        float2 hi = {z2, z3};
                        *(float2*)po       = lo;
                        *(float2*)(po + 2) = hi;
                    } else {
                        if (cb + 0 < WO) po[0] = z0;
                        if (cb + 1 < WO) po[1] = z1;
                        if (cb + 2 < WO) po[2] = z2;
                        if (cb + 3 < WO) po[3] = z3;
                    }
                }
            }
        }
    }
}

// ---------- D: bfrag-build ablation x16 ----------
__global__ __launch_bounds__(256, 2) void kan_d_bfrag(
    const float* __restrict__ bw, const float* __restrict__ sw,
    const float* __restrict__ sc)
{
    const int lane = threadIdx.x & 63;
    const int kb   = lane >> 4;
    for (int rep = 0; rep < 16; ++rep) {
        int nn = lane & 15;
        asm volatile("" : "+v"(nn));          // defeat CSE across reps
        f16x8 bfrag[3][2];
        build_bfrag(nn, kb, bw, sw, sc, bfrag);
        #pragma unroll
        for (int ki = 0; ki < 3; ++ki)
            #pragma unroll
            for (int kjp = 0; kjp < 2; ++kjp)
                asm volatile("" :: "v"(bfrag[ki][kjp]));   // keep-alive
    }
}

// ---------- B: stage1 (features + LDS writes) ablation x3 ----------
__global__ __launch_bounds__(256, 2) void kan_b_stage1(
    const float* __restrict__ x, const float* __restrict__ grid_)
{
    __shared__ __align__(16) f16 feat[12032];
    const int tid  = threadIdx.x;
    const int lane = tid & 63;
    const int w    = tid >> 6;
    f16* wfeat = &feat[w * 2880];
    const int gid   = blockIdx.x * 4 + w;
    const int plane = gid >> 3;
    const int chunk = gid & 7;
    const int r0    = chunk * 8;
    const float g0    = grid_[0];
    const float inv_h = 1.0f / (grid_[1] - grid_[0]);

    for (int rep = 0; rep < 3; ++rep) {
        int off = 0;
        asm volatile("" : "+v"(off));         // opaque -> loads re-issue
        const float* xp = x + (size_t)plane * 4096 + off;
        for (int s = 0; s < 4; ++s)
            stage1(wfeat, xp, r0, s * 16, lane, g0, inv_h);
        float rb = (float)wfeat[(lane * 16 + rep) % 2880];
        asm volatile("" :: "v"(rb));          // keep LDS stores live
    }
}

// ---------- C: stage2 (LDS reads + MFMA) ablation x6 ----------
__global__ __launch_bounds__(256, 2) void kan_c_mfma(
    const float* __restrict__ bw, const float* __restrict__ sw,
    const float* __restrict__ sc)
{
    __shared__ __align__(16) f16 feat[12032];   // intentionally uninitialized
    const int tid  = threadIdx.x;
    const int lane = tid & 63;
    const int w    = tid >> 6;
    f16* wfeat = &feat[w * 2880];
    const int nn    = lane & 15;
    const int kb    = lane >> 4;
    const int mI    = lane & 15;
    const int khalf = kb & 1;
    const int cAdd  = kb >> 1;

    f16x8 bfrag[3][2];
    build_bfrag(nn, kb, bw, sw, sc, bfrag);

    for (int rep = 0; rep < 6; ++rep) {
        int aBase = (mI + cAdd) * 16 + khalf * 8;
        asm volatile("" : "+v"(aBase));       // opaque -> ds_reads re-issue
        for (int s = 0; s < 4; ++s) {
            f16x8 af[3][2];
            #pragma unroll
            for (int kjp = 0; kjp < 2; ++kjp) {
                af[0][kjp] = *(const f16x8*)&wfeat[aBase + kjp * 32 + 0 * 288];
                af[1][kjp] = *(const f16x8*)&wfeat[aBase + kjp * 32 + 1 * 288];
            }
            #pragma unroll
            for (int i = 0; i < 8; ++i) {
                #pragma unroll
                for (int kjp = 0; kjp < 2; ++kjp)
                    af[(i + 2) % 3][kjp] =
                        *(const f16x8*)&wfeat[aBase + kjp * 32 + (i + 2) * 288];
                f32x4 acc = {0.f, 0.f, 0.f, 0.f};
                #pragma unroll
                for (int ki = 0; ki < 3; ++ki)
                    #pragma unroll
                    for (int kjp = 0; kjp < 2; ++kjp)
                        acc = __builtin_amdgcn_mfma_f32_16x16x32_f16(
                                  af[(i + ki) % 3][kjp], bfrag[ki][kjp], acc, 0, 0, 0);
                asm volatile("" :: "v"(acc)); // keep-alive, no stores
            }
        }
    }
}

extern "C" void kernel_launch(void* const* d_in, const int* in_sizes, int n_in,
                              void* d_out, int out_size, void* d_ws, size_t ws_size,
                              hipStream_t stream) {
    const float* x    = (const float*)d_in[0];
    const float* grid = (const float*)d_in[1];
    const float* bw   = (const float*)d_in[2];
    const float* sw   = (const float*)d_in[3];
    const float* sc   = (const float*)d_in[4];
    float* out = (float*)d_out;
    float* wsf = (float*)d_ws;

    kan_e_store<<<512, 256, 0, stream>>>(wsf);                      // store ablation
    kan_f<<<512, 256, 0, stream>>>(x, grid, bw, sw, sc, out);       // real kernel
    kan_d_bfrag<<<512, 256, 0, stream>>>(bw, sw, sc);               // bfrag ablation
    kan_b_stage1<<<512, 256, 0, stream>>>(x, grid);                 // stage1 ablation
    kan_c_mfma<<<512, 256, 0, stream>>>(bw, sw, sc);                // stage2 ablation
}

// Round 10
// 79.516 us; speedup vs baseline: 2.6955x; 2.6955x over previous
//
#include <hip/hip_runtime.h>

typedef _Float16 f16;
typedef _Float16 f16x8 __attribute__((ext_vector_type(8)));
typedef float    f32x4 __attribute__((ext_vector_type(4)));

#define HO 62
#define WO 62

// ---------- prep: fold weights into the per-lane MFMA B-fragment image ----------
// ws[q*64 + lane], q = ki*2 + kjp. Runs once; main kernel loads 6 x dwordx4.
__global__ __launch_bounds__(384) void kan_prep(
    const float* __restrict__ bw, const float* __restrict__ sw,
    const float* __restrict__ sc, f16x8* __restrict__ ws)
{
    const int tid  = threadIdx.x;        // 0..383
    const int lane = tid & 63;
    const int q    = tid >> 6;           // 0..5
    const int ki   = q >> 1;
    const int kjp  = q & 1;
    const int nn   = lane & 15;
    const int kb   = lane >> 4;
    f16x8 bf;
    #pragma unroll
    for (int e = 0; e < 8; ++e) {
        const int k    = kb * 8 + e;
        const int kj   = kjp * 2 + (k >> 4);
        const int slot = k & 15;
        float wv = 0.0f;
        if (nn < 8 && kj < 3 && slot < 9) {
            const int kk = ki * 3 + kj;
            wv = (slot == 0) ? bw[nn * 9 + kk]
                             : sw[(nn * 9 + kk) * 8 + (slot - 1)] * sc[nn * 9 + kk];
        }
        bf[e] = (f16)wv;
    }
    ws[q * 64 + lane] = bf;
}

// ---------- main: barrier-free wave-private MFMA KAN conv ----------
// 2048 blocks x 256 thr (4 waves). Wave unit = (plane, row-chunk, col-tile):
// 256 x 8 x 4 = 8192 units. Wave builds features for its 10x18 input tile in
// its private LDS slice (16 f16 slots/pixel: slot0 silu, 1..8 spline bases),
// then 6 MFMAs x 8 output rows. No __syncthreads anywhere.
#define SLICE 2896   // 2880 + 16 zeroed pad (covers kjp=1 col-17 edge read)
__global__ __launch_bounds__(256, 4) void kan_main(
    const float* __restrict__ x,     // (256, 64, 64)
    const float* __restrict__ grid_, // (9, 12) uniform knots
    const f16x8* __restrict__ ws,    // prep output
    float* __restrict__ out)         // (256*8, 62, 62)
{
    __shared__ __align__(16) f16 feat[4 * SLICE];

    const int tid  = threadIdx.x;
    const int lane = tid & 63;
    const int w    = tid >> 6;
    f16* wfeat = &feat[w * SLICE];

    const int unit  = blockIdx.x * 4 + w;   // 0..8191
    const int plane = unit >> 5;
    const int chunk = (unit >> 2) & 7;
    const int s     = unit & 3;
    const int r0    = chunk * 8;            // output rows r0..r0+7 (masked >=62)
    const int c0    = s * 16;               // output cols c0..c0+15

    // ---- B fragments: 6 coalesced 16B loads (replaces 48-scalar-load build)
    f16x8 bfrag[3][2];
    #pragma unroll
    for (int q = 0; q < 6; ++q)
        bfrag[q >> 1][q & 1] = ws[q * 64 + lane];

    // ---- zero the slice pad (16 f16 = one b32x8; lanes 0..1 only)
    if (lane < 2)
        *(f16x8*)&wfeat[2880 + lane * 8] = (f16x8){(f16)0.f,(f16)0.f,(f16)0.f,(f16)0.f,
                                                   (f16)0.f,(f16)0.f,(f16)0.f,(f16)0.f};

    // ---- stage 1: features for the wave's 10x18 tile (wave-private)
    const float g0    = grid_[0];
    const float inv_h = 1.0f / (grid_[1] - grid_[0]);
    const float* xp   = x + (size_t)plane * 4096;

    #pragma unroll
    for (int it = 0; it < 3; ++it) {
        const int p = it * 64 + lane;
        if (p < 180) {
            const int row = p / 18;
            const int col = p - row * 18;
            int gy = r0 + row; gy = (gy < 64) ? gy : 63;   // clamped pixels feed
            int gx = c0 + col; gx = (gx < 64) ? gx : 63;   // only masked outputs
            const float xv = xp[gy * 64 + gx];

            const float si = xv / (1.0f + __expf(-xv));
            const float u  = (xv - g0) * inv_h;
            int j = (int)floorf(u);
            j = (j < 3) ? 3 : ((j > 7) ? 7 : j);
            const float t   = u - (float)j;
            const float omt = 1.0f - t;
            const float t2  = t * t;
            const float t3  = t2 * t;
            const float c6  = 1.0f / 6.0f;
            const float bv0 = omt * omt * omt * c6;
            const float bv1 = (3.0f * t3 - 6.0f * t2 + 4.0f) * c6;
            const float bv2 = (-3.0f * t3 + 3.0f * t2 + 3.0f * t + 1.0f) * c6;
            const float bv3 = t3 * c6;

            f16* fp = &wfeat[p * 16];
            f16x8 z0 = {(f16)si, (f16)0.f, (f16)0.f, (f16)0.f,
                        (f16)0.f, (f16)0.f, (f16)0.f, (f16)0.f};
            f16x8 z1 = {(f16)0.f, (f16)0.f, (f16)0.f, (f16)0.f,
                        (f16)0.f, (f16)0.f, (f16)0.f, (f16)0.f};
            *(f16x8*)fp       = z0;          // slots 0-7 (slot0 = silu)
            *(f16x8*)(fp + 8) = z1;          // slots 8-15
            fp[j - 2] = (f16)bv0;            // scatter slots j-2..j+1 (1..8)
            fp[j - 1] = (f16)bv1;
            fp[j]     = (f16)bv2;
            fp[j + 1] = (f16)bv3;
        }
    }
    // NO __syncthreads — wave reads only its own writes (lgkmcnt ordering).

    // ---- stage 2: 8 output rows x 16 cols x 8 v via 6 MFMAs/row
    const int mI    = lane & 15;    // A row = out col; D col = v (same bits as nn)
    const int kb    = lane >> 4;
    const int nn    = mI;
    const int khalf = kb & 1;
    const int cAdd  = kb >> 1;
    const int aBase = (mI + cAdd) * 16 + khalf * 8;

    f16x8 af[3][2];                 // rolling A rows (row r at af[r % 3])
    #pragma unroll
    for (int kjp = 0; kjp < 2; ++kjp) {
        af[0][kjp] = *(const f16x8*)&wfeat[aBase + kjp * 32 + 0 * 288];
        af[1][kjp] = *(const f16x8*)&wfeat[aBase + kjp * 32 + 1 * 288];
    }

    #pragma unroll
    for (int i = 0; i < 8; ++i) {
        #pragma unroll
        for (int kjp = 0; kjp < 2; ++kjp)
            af[(i + 2) % 3][kjp] =
                *(const f16x8*)&wfeat[aBase + kjp * 32 + (i + 2) * 288];

        f32x4 acc = {0.f, 0.f, 0.f, 0.f};
        #pragma unroll
        for (int ki = 0; ki < 3; ++ki)
            #pragma unroll
            for (int kjp = 0; kjp < 2; ++kjp)
                acc = __builtin_amdgcn_mfma_f32_16x16x32_f16(
                          af[(i + ki) % 3][kjp], bfrag[ki][kjp], acc, 0, 0, 0);

        const int ho = r0 + i;
        if (nn < 8 && ho < HO) {
            const int cb = c0 + kb * 4;
            float* po = out + ((size_t)(plane * 8 + nn) * (HO * WO)) + ho * WO + cb;
            if (cb + 3 < WO) {
                float2 lo = {acc[0], acc[1]};
                float2 hi = {acc[2], acc[3]};
                *(float2*)po       = lo;
                *(float2*)(po + 2) = hi;
            } else {
                #pragma unroll
                for (int q = 0; q < 4; ++q)
                    if (cb + q < WO) po[q] = acc[q];
            }
        }
    }
}

extern "C" void kernel_launch(void* const* d_in, const int* in_sizes, int n_in,
                              void* d_out, int out_size, void* d_ws, size_t ws_size,
                              hipStream_t stream) {
    const float* x    = (const float*)d_in[0];
    const float* grid = (const float*)d_in[1];
    const float* bw   = (const float*)d_in[2];
    const float* sw   = (const float*)d_in[3];
    const float* sc   = (const float*)d_in[4];
    float* out = (float*)d_out;
    f16x8* ws  = (f16x8*)d_ws;

    kan_prep<<<1, 384, 0, stream>>>(bw, sw, sc, ws);
    kan_main<<<2048, 256, 0, stream>>>(x, grid, ws, out);
}